// Round 12
// baseline (4811.262 us; speedup 1.0000x reference)
//
#include <hip/hip_runtime.h>

#define LOWV (-10000.0f)
typedef unsigned long long u64;

__device__ __forceinline__ float sigf(float x){ return 1.0f/(1.0f+expf(-x)); }
__device__ __forceinline__ unsigned fkey(float f){
    unsigned u = __float_as_uint(f);
    return (u & 0x80000000u) ? ~u : (u | 0x80000000u);
}
__device__ __forceinline__ float funkey(unsigned k){
    unsigned u = (k & 0x80000000u) ? (k ^ 0x80000000u) : ~k;
    return __uint_as_float(u);
}

// ---------- k_rm: WT6[(c/6)][k][6] from gate-interleaved Wh|Wpred ; W8[(c/8)][k][8] from Wout ----------
__global__ __launch_bounds__(256) void k_rm(const float* __restrict__ Wh, const float* __restrict__ Wpred,
        const float* __restrict__ Wout, float* __restrict__ WT6, float* __restrict__ W8){
    long long idx = (long long)blockIdx.x*256 + threadIdx.x;
    const long long N1 = 3072LL*640;
    if (idx < N1){
        int c = (int)(idx % 3072), k = (int)(idx / 3072);
        float v = (c < 2560) ? Wh[(size_t)k*2560 + (c&3)*640 + (c>>2)]   // c = j*4+g
                             : Wpred[(size_t)k*512 + (c-2560)];
        WT6[(size_t)(c/6)*3840 + k*6 + (c%6)] = v;
    } else {
        long long i2 = idx - N1;
        if (i2 < 1024LL*512){
            int c = (int)(i2 % 1024), k = (int)(i2 / 1024);
            W8[(size_t)(c>>3)*4096 + k*8 + (c&7)] = Wout[(size_t)k*1024 + c];
        }
    }
}

// ---------- k_trE: WencT[512][1024] tiled transpose ----------
__global__ __launch_bounds__(256) void k_trE(const float* __restrict__ Wenc, float* __restrict__ WencT){
    __shared__ float t[64][65];
    int b = blockIdx.x, tr = b/8, tc = b%8;
    int tx = threadIdx.x & 63, ty0 = threadIdx.x >> 6;
    #pragma unroll
    for (int i = 0; i < 16; ++i){
        int row = i*4 + ty0;
        t[row][tx] = Wenc[(size_t)(tr*64 + row)*512 + tc*64 + tx];
    }
    __syncthreads();
    #pragma unroll
    for (int i = 0; i < 16; ++i){
        int row = i*4 + ty0;
        WencT[(size_t)(tc*64 + row)*1024 + tr*64 + tx] = t[tx][row];
    }
}

// ---------- k_ewi: EWi4[v*640+j] = float4 gates of E@Wi + bi + bh ----------
__global__ __launch_bounds__(256) void k_ewi(const float* __restrict__ E, const float* __restrict__ Wi,
        const float* __restrict__ bi, const float* __restrict__ bh, float4* __restrict__ EWi4){
    int tid = threadIdx.x, lane = tid & 63, wvv = tid >> 6;
    int vb = blockIdx.x / 10, jb = blockIdx.x % 10;   // 1280 blocks
    int j = jb*64 + lane;
    int v0 = vb*8 + wvv*2;
    float acc[2][4];
    #pragma unroll
    for (int i=0;i<2;++i)
        #pragma unroll
        for (int g=0;g<4;++g) acc[i][g] = 0.f;
    for (int k0 = 0; k0 < 512; k0 += 4){
        float ev[2][4];
        #pragma unroll
        for (int i=0;i<2;++i) *(float4*)ev[i] = *(const float4*)(E + (size_t)(v0+i)*512 + k0);
        #pragma unroll
        for (int kk=0;kk<4;++kk){
            const float* wr = Wi + (size_t)(k0+kk)*2560 + j;
            float w0 = wr[0], w1 = wr[640], w2 = wr[1280], w3 = wr[1920];
            #pragma unroll
            for (int i=0;i<2;++i){
                acc[i][0] += ev[i][kk]*w0; acc[i][1] += ev[i][kk]*w1;
                acc[i][2] += ev[i][kk]*w2; acc[i][3] += ev[i][kk]*w3;
            }
        }
    }
    float b0 = bi[j] + bh[j], b1 = bi[640+j] + bh[640+j];
    float b2 = bi[1280+j] + bh[1280+j], b3 = bi[1920+j] + bh[1920+j];
    #pragma unroll
    for (int i=0;i<2;++i)
        EWi4[(size_t)(v0+i)*640 + j] = make_float4(acc[i][0]+b0, acc[i][1]+b1, acc[i][2]+b2, acc[i][3]+b3);
}

// ---------- k_is: frame-0 encP | zero packed/sumexp | h0/c0 | scalar state ----------
__global__ __launch_bounds__(512) void k_is(const float* __restrict__ enc, const int* __restrict__ lens,
        const float* __restrict__ WencT, const float4* __restrict__ EWi4,
        float* __restrict__ encPT, float* __restrict__ hT, float* __restrict__ cT,
        u64* __restrict__ packedP, float* __restrict__ sumexpP,
        int* __restrict__ actA, int* __restrict__ encTA, int* __restrict__ nEmA, float* __restrict__ scoresA){
    __shared__ float sWe[6*1024];
    int bid = blockIdx.x, tid = threadIdx.x, lane = tid & 63, wv = tid >> 6;
    if (bid < 86){
        int ec0 = bid*6, nc = (512 - ec0) < 6 ? (512 - ec0) : 6;
        for (int i = tid; i < nc*1024; i += 512) sWe[i] = WencT[(size_t)ec0*1024 + i];
        __syncthreads();
        for (int r = wv; r < 128; r += 8){
            const float* er = enc + (size_t)r*160*1024;   // frame 0
            float a[6] = {0,0,0,0,0,0};
            int k4 = lane*4;
            #pragma unroll
            for (int i = 0; i < 4; ++i){
                int k = i*256 + k4;
                float4 ev = *(const float4*)(er + k);
                for (int cc = 0; cc < nc; ++cc){
                    float4 w4 = *(const float4*)(sWe + cc*1024 + k);
                    a[cc] += ev.x*w4.x + ev.y*w4.y + ev.z*w4.z + ev.w*w4.w;
                }
            }
            for (int cc = 0; cc < nc; ++cc){
                #pragma unroll
                for (int off = 32; off; off >>= 1) a[cc] += __shfl_xor(a[cc], off, 64);
                if (lane == 0) encPT[(size_t)(ec0+cc)*128 + r] = a[cc];
            }
        }
    } else if (bid < 98){
        int idx = (bid-86)*512 + tid;   // 6144
        packedP[(size_t)idx*8] = 0ull;
        sumexpP[(size_t)idx*16] = 0.f;
    } else if (bid < 130){
        int jb = bid - 98;
        for (int u = tid; u < 2560; u += 512){
            int j = jb*20 + (u >> 7), r = u & 127;
            float4 e0 = EWi4[j];
            float c0v = sigf(e0.x)*tanhf(e0.z);
            float h0v = tanhf(c0v)*sigf(e0.w);
            cT[(size_t)j*128 + r] = c0v;
            hT[(size_t)j*128 + r] = h0v;
        }
    } else {
        if (tid < 128){ actA[tid] = 1; encTA[tid] = 0; nEmA[tid] = 0; scoresA[tid] = 0.f; }
    }
}

// ---------- P1: flat GEMV 3072 cols (2560 gates | 512 joint), 6 cols/block ----------
__global__ __launch_bounds__(512) void kP1(int s, const float* __restrict__ WT6, const float* __restrict__ hT,
        const float* __restrict__ encPT, const float* __restrict__ bj,
        float* __restrict__ gT, float* __restrict__ jointT){
    __shared__ float sXP[4*6*128];
    int bid = blockIdx.x, tid = threadIdx.x;
    int p = s & 1;
    int ks = tid >> 7, r = tid & 127;
    const float* hp = hT + (size_t)p*81920;
    const float* wb = WT6 + (size_t)bid*3840;
    float acc[6] = {0,0,0,0,0,0};
    int k0 = ks*160;
    #pragma unroll 4
    for (int k = k0; k < k0 + 160; ++k){
        float h = hp[(size_t)k*128 + r];
        const float* wk = wb + k*6;
        float2 wa = *(const float2*)(wk);
        float2 wc = *(const float2*)(wk + 2);
        float2 we = *(const float2*)(wk + 4);
        acc[0] += h*wa.x; acc[1] += h*wa.y;
        acc[2] += h*wc.x; acc[3] += h*wc.y;
        acc[4] += h*we.x; acc[5] += h*we.y;
    }
    #pragma unroll
    for (int c = 0; c < 6; ++c) sXP[c*512 + ks*128 + r] = acc[c];
    __syncthreads();
    for (int u = tid; u < 768; u += 512){
        int c = u >> 7, rr = u & 127;
        const float* q = sXP + c*512 + rr;
        float v = q[0] + q[128] + q[256] + q[384];
        int col = bid*6 + c;
        if (col < 2560){
            gT[(size_t)col*128 + rr] = v;
        } else {
            int cj = col - 2560;
            jointT[(size_t)cj*128 + rr] = tanhf(v + encPT[(size_t)cj*128 + rr] + bj[cj]);
        }
    }
}

// ---------- P2: logits 8 cols/block + per-row padded atomic argmax/sumexp ----------
__global__ __launch_bounds__(512) void kP2(int s, const float* __restrict__ W8, const float* __restrict__ jointT,
        const int* __restrict__ nEmA, u64* __restrict__ packedP, float* __restrict__ sumexpP){
    __shared__ float sXP[4*8*128];
    __shared__ u64 kx[8*128];
    __shared__ float exs[8*128];
    int bid = blockIdx.x, tid = threadIdx.x;
    int p = s & 1;
    int ks = tid >> 7, r = tid & 127;
    const float* w8 = W8 + (size_t)bid*4096;
    float acc[8] = {0,0,0,0,0,0,0,0};
    int k0 = ks*128;
    #pragma unroll 4
    for (int k = k0; k < k0 + 128; ++k){
        float jv = jointT[(size_t)k*128 + r];
        const float* wk = w8 + k*8;
        float4 wa = *(const float4*)(wk);
        float4 wb = *(const float4*)(wk + 4);
        acc[0] += jv*wa.x; acc[1] += jv*wa.y; acc[2] += jv*wa.z; acc[3] += jv*wa.w;
        acc[4] += jv*wb.x; acc[5] += jv*wb.y; acc[6] += jv*wb.z; acc[7] += jv*wb.w;
    }
    #pragma unroll
    for (int c = 0; c < 8; ++c) sXP[c*512 + ks*128 + r] = acc[c];
    __syncthreads();
    for (int u = tid; u < 1024; u += 512){
        int c = u >> 7, rr = u & 127;
        const float* q = sXP + c*512 + rr;
        float lg = q[0] + q[128] + q[256] + q[384];
        float ex = expf(lg);
        int col = bid*8 + c;
        bool force = nEmA[p*128 + rr] >= 2;
        int idx; float va;
        if (col == 0){ idx = 1024; va = lg; }
        else { idx = col; va = force ? LOWV : lg; }
        kx[c*128 + rr] = ((u64)fkey(va) << 32) | (unsigned)(2047 - idx);
        exs[c*128 + rr] = ex;
    }
    __syncthreads();
    if (tid < 128){
        u64 m = kx[tid]; float es = exs[tid];
        #pragma unroll
        for (int q2 = 1; q2 < 8; ++q2){
            u64 o = kx[q2*128 + tid]; if (o > m) m = o;
            es += exs[q2*128 + tid];
        }
        atomicMax(&packedP[((size_t)s*128 + tid)*8], m);
        atomicAdd(&sumexpP[((size_t)s*128 + tid)*16], es);
    }
}

// ---------- P3: LSTM pointwise | lazy enc-proj | state machine + out ----------
__global__ __launch_bounds__(512) void kP3(int s, const float* __restrict__ enc, const int* __restrict__ lens,
        const float* __restrict__ WencT, const float4* __restrict__ EWi4,
        float* __restrict__ hT, float* __restrict__ cT, float* __restrict__ encPT, const float* __restrict__ gT,
        const u64* __restrict__ packedP, const float* __restrict__ sumexpP,
        int* __restrict__ actA, int* __restrict__ encTA, int* __restrict__ nEmA, float* __restrict__ scoresA,
        float* __restrict__ out){
    __shared__ float sWe[6*1024];
    __shared__ int sT[128], sU[128], sA2[128];
    int bid = blockIdx.x, tid = threadIdx.x, lane = tid & 63, wv = tid >> 6;
    int p = s & 1, w = 1 - p;
    if (bid < 160){
        if (tid < 128){
            u64 pk = packedP[((size_t)s*128 + tid)*8];
            int tok = 2047 - (int)(unsigned)(pk & 0xffffffffu);
            sT[tid] = tok < 1023 ? tok : 1023;
            sU[tid] = (actA[p*128 + tid] && tok != 1024) ? 1 : 0;
        }
        __syncthreads();
        int j = bid*4 + (tid >> 7), r = tid & 127;
        float h2;
        if (sU[r]){
            float4 ew = EWi4[(size_t)sT[r]*640 + j];
            float gi = gT[(size_t)(4*j + 0)*128 + r] + ew.x;
            float gf = gT[(size_t)(4*j + 1)*128 + r] + ew.y;
            float gg = gT[(size_t)(4*j + 2)*128 + r] + ew.z;
            float go = gT[(size_t)(4*j + 3)*128 + r] + ew.w;
            float cold = cT[(size_t)j*128 + r];
            float cn = sigf(gf)*cold + sigf(gi)*tanhf(gg);
            h2 = tanhf(cn)*sigf(go);
            cT[(size_t)j*128 + r] = cn;
        } else {
            h2 = hT[(size_t)p*81920 + (size_t)j*128 + r];
        }
        hT[(size_t)w*81920 + (size_t)j*128 + r] = h2;
    } else if (bid < 246){
        int ec0 = (bid - 160)*6, nc = (512 - ec0) < 6 ? (512 - ec0) : 6;
        for (int i = tid; i < nc*1024; i += 512) sWe[i] = WencT[(size_t)ec0*1024 + i];
        if (tid < 128){
            u64 pk = packedP[((size_t)s*128 + tid)*8];
            int tok = 2047 - (int)(unsigned)(pk & 0xffffffffu);
            int adv = -1;
            if (actA[p*128 + tid] && tok == 1024){
                int e2 = encTA[p*128 + tid] + 1;
                if (e2 < lens[tid]) adv = e2;
            }
            sA2[tid] = adv;
        }
        __syncthreads();
        for (int r = wv; r < 128; r += 8){
            int t = sA2[r];
            if (t < 0) continue;
            const float* er = enc + ((size_t)r*160 + t)*1024;
            float a[6] = {0,0,0,0,0,0};
            int k4 = lane*4;
            #pragma unroll
            for (int i = 0; i < 4; ++i){
                int k = i*256 + k4;
                float4 ev = *(const float4*)(er + k);
                for (int cc = 0; cc < nc; ++cc){
                    float4 w4 = *(const float4*)(sWe + cc*1024 + k);
                    a[cc] += ev.x*w4.x + ev.y*w4.y + ev.z*w4.z + ev.w*w4.w;
                }
            }
            for (int cc = 0; cc < nc; ++cc){
                #pragma unroll
                for (int off = 32; off; off >>= 1) a[cc] += __shfl_xor(a[cc], off, 64);
                if (lane == 0) encPT[(size_t)(ec0+cc)*128 + r] = a[cc];
            }
        }
    } else {
        if (tid < 128){
            int r = tid;
            u64 pk = packedP[((size_t)s*128 + r)*8];
            float se = sumexpP[((size_t)s*128 + r)*16];
            int act = actA[p*128 + r];
            int et  = encTA[p*128 + r];
            int ne  = nEmA[p*128 + r];
            float sc = scoresA[p*128 + r];
            int len = lens[r];
            int tok_out = 1024, act_n = 0;
            if (act){
                int tok = 2047 - (int)(unsigned)(pk & 0xffffffffu);
                float chosen = funkey((unsigned)(pk >> 32));
                float tlp = chosen - logf(se);
                int isb = (tok == 1024);
                sc += tlp;
                et += isb ? 1 : 0;
                ne  = isb ? 0 : ne + 1;
                act_n = (et < len) ? 1 : 0;
                tok_out = (act_n || isb) ? tok : 1024;
            }
            actA[w*128 + r] = act_n;
            encTA[w*128 + r] = et;
            nEmA[w*128 + r] = ne;
            scoresA[w*128 + r] = sc;
            out[(size_t)r*48 + s] = (float)tok_out;
            if (s == 47) out[6144 + r] = sc;
        }
    }
}

extern "C" void kernel_launch(void* const* d_in, const int* in_sizes, int n_in,
                              void* d_out, int out_size, void* d_ws, size_t ws_size,
                              hipStream_t stream) {
    const float* enc   = (const float*)d_in[0];
    const int*   lens  = (const int*)  d_in[1];
    const float* E     = (const float*)d_in[3];
    const float* Wi    = (const float*)d_in[4];
    const float* Wh    = (const float*)d_in[5];
    const float* bi    = (const float*)d_in[6];
    const float* bh    = (const float*)d_in[7];
    const float* Wenc  = (const float*)d_in[8];
    const float* Wpred = (const float*)d_in[9];
    const float* bj    = (const float*)d_in[10];
    const float* Wout  = (const float*)d_in[11];
    float* out = (float*)d_out;

    char* base = (char*)d_ws;
    size_t off = 0;
    auto carve = [&](size_t bytes) -> void* {
        void* pp = base + off;
        off += (bytes + 255) & ~(size_t)255;
        return pp;
    };
    float*  WT6   = (float*)carve((size_t)512*640*6*4);    // 7.9 MB
    float*  W8    = (float*)carve((size_t)128*512*8*4);    // 2.1 MB
    float*  WencT = (float*)carve((size_t)512*1024*4);     // 2 MB
    float4* EWi4  = (float4*)carve((size_t)1024*640*16);   // 10.5 MB
    float*  hT    = (float*)carve((size_t)2*640*128*4);
    float*  cT    = (float*)carve((size_t)640*128*4);
    float*  encPT = (float*)carve((size_t)512*128*4);
    float*  jointT= (float*)carve((size_t)512*128*4);
    float*  gT    = (float*)carve((size_t)2560*128*4);     // 1.3 MB
    u64*    packedP = (u64*)carve((size_t)48*128*8*8);     // 64B/row
    float*  sumexpP = (float*)carve((size_t)48*128*16*4);  // 64B/row
    int*    actA  = (int*)carve(2*128*4);
    int*    encTA = (int*)carve(2*128*4);
    int*    nEmA  = (int*)carve(2*128*4);
    float*  scoresA = (float*)carve(2*128*4);
    (void)ws_size; (void)in_sizes; (void)n_in; (void)out_size;

    k_rm <<<9728, 256, 0, stream>>>(Wh, Wpred, Wout, WT6, W8);
    k_trE<<<128,  256, 0, stream>>>(Wenc, WencT);
    k_ewi<<<1280, 256, 0, stream>>>(E, Wi, bi, bh, EWi4);
    k_is <<<131,  512, 0, stream>>>(enc, lens, WencT, EWi4, encPT, hT, cT,
                                    packedP, sumexpP, actA, encTA, nEmA, scoresA);
    for (int s = 0; s < 48; ++s){
        kP1<<<512, 512, 0, stream>>>(s, WT6, hT, encPT, bj, gT, jointT);
        kP2<<<128, 512, 0, stream>>>(s, W8, jointT, nEmA, packedP, sumexpP);
        kP3<<<247, 512, 0, stream>>>(s, enc, lens, WencT, EWi4, hT, cT, encPT, gT,
                                     packedP, sumexpP, actA, encTA, nEmA, scoresA, out);
    }
}

// Round 13
// 1971.464 us; speedup vs baseline: 2.4405x; 2.4405x over previous
//
#include <hip/hip_runtime.h>

#define LOWV (-10000.0f)
#define NBLK 256
typedef unsigned long long u64;

__device__ __forceinline__ float sigf(float x){ return 1.0f/(1.0f+expf(-x)); }
__device__ __forceinline__ unsigned fkey(float f){
    unsigned u = __float_as_uint(f);
    return (u & 0x80000000u) ? ~u : (u | 0x80000000u);
}
__device__ __forceinline__ float funkey(unsigned k){
    unsigned u = (k & 0x80000000u) ? (k ^ 0x80000000u) : ~k;
    return __uint_as_float(u);
}
__device__ __forceinline__ float aload_f (const float* p){ return __hip_atomic_load(p, __ATOMIC_RELAXED, __HIP_MEMORY_SCOPE_AGENT); }
__device__ __forceinline__ u64   aload_u64(const u64* p){ return __hip_atomic_load(p, __ATOMIC_RELAXED, __HIP_MEMORY_SCOPE_AGENT); }
__device__ __forceinline__ void  astore_f(float* p, float v){ __hip_atomic_store(p, v, __ATOMIC_RELAXED, __HIP_MEMORY_SCOPE_AGENT); }
__device__ __forceinline__ void  astore_u64(u64* p, u64 v){ __hip_atomic_store(p, v, __ATOMIC_RELAXED, __HIP_MEMORY_SCOPE_AGENT); }

typedef __attribute__((ext_vector_type(4))) float f32x4;
#define GLD4(d, p) asm volatile("global_load_dwordx4 %0, %1, off sc0 sc1" : "=v"(d) : "v"(p))
#define WAIT0 do{ asm volatile("s_waitcnt vmcnt(0)" ::: "memory"); __builtin_amdgcn_sched_barrier(0); }while(0)

// ---------- WT24[cgrp][k][24]: col c<2560 -> Wh gate-interleaved (j=c>>2,g=c&3); c>=2560 -> Wpred ----------
__global__ __launch_bounds__(256) void k_rm(const float* __restrict__ Wh, const float* __restrict__ Wpred,
        float* __restrict__ WT24, int* __restrict__ cntZ){
    if (blockIdx.x == 0){ for (int i = threadIdx.x; i < 544; i += 256) cntZ[i] = 0; }
    long long idx = (long long)blockIdx.x*256 + threadIdx.x;
    if (idx >= 3072LL*640) return;
    int c = (int)(idx % 3072), k = (int)(idx / 3072);
    float v = (c < 2560) ? Wh[(size_t)k*2560 + (c&3)*640 + (c>>2)]
                         : Wpred[(size_t)k*512 + (c-2560)];
    WT24[(size_t)(c/24)*(640*24) + k*24 + (c%24)] = v;
}

// ---------- WencT[512][1024] tiled transpose ----------
__global__ __launch_bounds__(256) void k_trE(const float* __restrict__ Wenc, float* __restrict__ WencT){
    __shared__ float t[64][65];
    int b = blockIdx.x, tr = b/8, tc = b%8;
    int tx = threadIdx.x & 63, ty0 = threadIdx.x >> 6;
    #pragma unroll
    for (int i = 0; i < 16; ++i){
        int row = i*4 + ty0;
        t[row][tx] = Wenc[(size_t)(tr*64 + row)*512 + tc*64 + tx];
    }
    __syncthreads();
    #pragma unroll
    for (int i = 0; i < 16; ++i){
        int row = i*4 + ty0;
        WencT[(size_t)(tc*64 + row)*1024 + tr*64 + tx] = t[tx][row];
    }
}

// ---------- EWi4[v*640+j] = float4 gates of E@Wi + bi + bh ----------
__global__ __launch_bounds__(256) void k_ewi(const float* __restrict__ E, const float* __restrict__ Wi,
        const float* __restrict__ bi, const float* __restrict__ bh, float4* __restrict__ EWi4){
    int tid = threadIdx.x, lane = tid & 63, wvv = tid >> 6;
    int vb = blockIdx.x / 10, jb = blockIdx.x % 10;
    int j = jb*64 + lane;
    int v0 = vb*8 + wvv*2;
    float acc[2][4];
    #pragma unroll
    for (int i=0;i<2;++i)
        #pragma unroll
        for (int g=0;g<4;++g) acc[i][g] = 0.f;
    for (int k0 = 0; k0 < 512; k0 += 4){
        float ev[2][4];
        #pragma unroll
        for (int i=0;i<2;++i) *(float4*)ev[i] = *(const float4*)(E + (size_t)(v0+i)*512 + k0);
        #pragma unroll
        for (int kk=0;kk<4;++kk){
            const float* wr = Wi + (size_t)(k0+kk)*2560 + j;
            float w0 = wr[0], w1 = wr[640], w2 = wr[1280], w3 = wr[1920];
            #pragma unroll
            for (int i=0;i<2;++i){
                acc[i][0] += ev[i][kk]*w0; acc[i][1] += ev[i][kk]*w1;
                acc[i][2] += ev[i][kk]*w2; acc[i][3] += ev[i][kk]*w3;
            }
        }
    }
    float b0 = bi[j] + bh[j], b1 = bi[640+j] + bh[640+j];
    float b2 = bi[1280+j] + bh[1280+j], b3 = bi[1920+j] + bh[1920+j];
    #pragma unroll
    for (int i=0;i<2;++i)
        EWi4[(size_t)(v0+i)*640 + j] = make_float4(acc[i][0]+b0, acc[i][1]+b1, acc[i][2]+b2, acc[i][3]+b3);
}

// ---------- k_is: frame-0 encP (bypass stores) ----------
__global__ __launch_bounds__(512) void k_is(const float* __restrict__ enc,
        const float* __restrict__ WencT, float* __restrict__ encPT){
    __shared__ float sWe[6*1024];
    int bid = blockIdx.x, tid = threadIdx.x, lane = tid & 63, wv = tid >> 6;
    int ec0 = bid*6, nc = (512 - ec0) < 6 ? (512 - ec0) : 6;
    for (int i = tid; i < nc*1024; i += 512) sWe[i] = WencT[(size_t)ec0*1024 + i];
    __syncthreads();
    for (int r = wv; r < 128; r += 8){
        const float* er = enc + (size_t)r*160*1024;
        float a[6] = {0,0,0,0,0,0};
        int k4 = lane*4;
        #pragma unroll
        for (int i = 0; i < 4; ++i){
            int k = i*256 + k4;
            float4 ev = *(const float4*)(er + k);
            for (int cc = 0; cc < nc; ++cc){
                float4 w4 = *(const float4*)(sWe + cc*1024 + k);
                a[cc] += ev.x*w4.x + ev.y*w4.y + ev.z*w4.z + ev.w*w4.w;
            }
        }
        for (int cc = 0; cc < nc; ++cc){
            #pragma unroll
            for (int off = 32; off; off >>= 1) a[cc] += __shfl_xor(a[cc], off, 64);
            if (lane == 0) astore_f(&encPT[(size_t)(ec0+cc)*128 + r], a[cc]);
        }
    }
}

// ---------- persistent decode: 256 blocks x 512 thr, low-import partition ----------
__global__ __launch_bounds__(512, 2) void mega(
    const float* __restrict__ enc, const int* __restrict__ lens, const float* __restrict__ bj,
    const float* __restrict__ WT24, const float* __restrict__ Wout, const float* __restrict__ WencT,
    const float4* __restrict__ EWi4,
    float* __restrict__ hT, float* __restrict__ encPT, float* __restrict__ jointT,
    u64* __restrict__ packedP, float* __restrict__ sumexpP,
    int* __restrict__ cntZ, float* __restrict__ out)
{
    __shared__ float sW[640*24];          // 61440B  P1 weights [k][24]
    __shared__ float sCh[8704];           // 34816B  chunk buffers / P1 partial-reduce alias
    __shared__ float sG[24*64];           // gates [cl][r]   (P1 -> P3)
    __shared__ float sC[6*64];            // c-state [jj][r] (persists)
    __shared__ float sP2[2048];           // P2/enc partials
    __shared__ u64   sKX[512];
    __shared__ float sEX[512];
    __shared__ int sAct[128], sEncT[128], sNEm[128], sLen[128], sTok[128], sUpd[128], sAdv[128];

    const int bid = blockIdx.x, tid = threadIdx.x, lane = tid & 63, wv = tid >> 6;
    const int cg = bid >> 1, rg = bid & 1, R0 = rg*64;
    const int jbase = cg*24;
    const int ngate = (jbase < 2560) ? ((2560 - jbase) < 24 ? (2560 - jbase) : 24) : 0;
    const int nj = ngate >> 2, j0 = jbase >> 2;
    const int lcg = cg & 63, rq = ((cg >> 6) << 1) | rg, RQ = rq*32;
    int ep = 0;
    float scReg = 0.f;

    auto gsync = [&](){
        asm volatile("s_waitcnt vmcnt(0)" ::: "memory");
        __syncthreads();
        ++ep;
        if (tid == 0){
            __hip_atomic_fetch_add(&cntZ[(bid & 15)*16], 1, __ATOMIC_RELAXED, __HIP_MEMORY_SCOPE_AGENT);
            if (bid < 16){
                while (__hip_atomic_load(&cntZ[bid*16], __ATOMIC_RELAXED, __HIP_MEMORY_SCOPE_AGENT) < ep*16)
                    __builtin_amdgcn_s_sleep(2);
                __hip_atomic_fetch_add(&cntZ[256], 1, __ATOMIC_RELAXED, __HIP_MEMORY_SCOPE_AGENT);
            }
            if (bid == 0){
                while (__hip_atomic_load(&cntZ[256], __ATOMIC_RELAXED, __HIP_MEMORY_SCOPE_AGENT) < ep*16)
                    __builtin_amdgcn_s_sleep(2);
                #pragma unroll
                for (int i = 0; i < 16; ++i)
                    __hip_atomic_store(&cntZ[272 + i*16], ep, __ATOMIC_RELAXED, __HIP_MEMORY_SCOPE_AGENT);
            } else {
                while (__hip_atomic_load(&cntZ[272 + (bid & 15)*16], __ATOMIC_RELAXED, __HIP_MEMORY_SCOPE_AGENT) < ep)
                    __builtin_amdgcn_s_sleep(4);
            }
        }
        __syncthreads();
    };

    // ---- stage P1 weights (cached) ----
    for (int i = tid; i < 15360; i += 512) sW[i] = WT24[(size_t)cg*15360 + i];
    if (tid < 128){ sAct[tid] = 1; sEncT[tid] = 0; sNEm[tid] = 0; sLen[tid] = lens[tid]; }
    __syncthreads();

    // ---- prologue: zero atomics, h0/c0 ----
    for (int i = tid; i < 24; i += 512){
        int idx = bid*24 + i;                       // 6144 = 48*128
        astore_u64(&packedP[(size_t)idx*8], 0ull);
        astore_f(&sumexpP[(size_t)idx*16], 0.f);
    }
    if (nj > 0 && tid < nj*64){
        int jj = tid >> 6, r = tid & 63;
        float4 e0 = EWi4[j0 + jj];
        float c0v = sigf(e0.x)*tanhf(e0.z);
        float h0v = tanhf(c0v)*sigf(e0.w);
        sC[jj*64 + r] = c0v;
        astore_f(&hT[(size_t)(j0+jj)*128 + R0 + r], h0v);
    }
    gsync();   // B0

    const int ksl = tid >> 7;            // P1: 4-way k-split
    const int ch  = (tid >> 6) & 1;      // P1: col-half (12 cols)
    const int rr1 = tid & 63;            // P1: row
    const int ks2 = tid >> 7;            // P2: 4-way k-split
    const int cq2 = (tid >> 5) & 3;      // P2: col-quad
    const int rr2 = tid & 31;            // P2: row

    for (int s = 0; s < 48; ++s){
        const int p = s & 1, w = 1 - p;
        const float* hp = hT + (size_t)p*81920;

        // ================= P1: 24 cols x 64 rows, h chunk-staged =================
        {
            float acc[12];
            #pragma unroll
            for (int q = 0; q < 12; ++q) acc[q] = 0.f;
            f32x4 bufA[2], bufB[2];
            // prefetch chunk 0
            #pragma unroll
            for (int i = 0; i < 2; ++i){
                int e4 = i*512 + tid;
                GLD4(bufA[i], hp + (size_t)(e4 >> 4)*128 + R0 + ((e4 & 15) << 2));
            }
            WAIT0;
            #pragma unroll
            for (int i = 0; i < 2; ++i){
                int e4 = i*512 + tid;
                float* d = sCh + (e4 >> 4)*66 + ((e4 & 15) << 2);
                *(float2*)d = make_float2(bufA[i].x, bufA[i].y);
                *(float2*)(d+2) = make_float2(bufA[i].z, bufA[i].w);
            }
            __syncthreads();
            int buf = 0;
            for (int c = 0; c < 10; ++c){
                if (c < 9){   // issue next chunk loads early (T14)
                    #pragma unroll
                    for (int i = 0; i < 2; ++i){
                        int e4 = i*512 + tid;
                        GLD4(bufB[i], hp + (size_t)((c+1)*64 + (e4 >> 4))*128 + R0 + ((e4 & 15) << 2));
                    }
                }
                const float* chb = sCh + buf*4224;
                #pragma unroll 4
                for (int kk = 0; kk < 16; ++kk){
                    int kl = ksl*16 + kk;
                    float h = chb[kl*66 + rr1];
                    const float* wk = sW + (size_t)(c*64 + kl)*24 + ch*12;
                    float4 wa = *(const float4*)(wk);
                    float4 wb = *(const float4*)(wk + 4);
                    float4 wc = *(const float4*)(wk + 8);
                    acc[0] += h*wa.x; acc[1] += h*wa.y; acc[2]  += h*wa.z; acc[3]  += h*wa.w;
                    acc[4] += h*wb.x; acc[5] += h*wb.y; acc[6]  += h*wb.z; acc[7]  += h*wb.w;
                    acc[8] += h*wc.x; acc[9] += h*wc.y; acc[10] += h*wc.z; acc[11] += h*wc.w;
                }
                if (c < 9){
                    WAIT0;
                    __syncthreads();
                    #pragma unroll
                    for (int i = 0; i < 2; ++i){
                        int e4 = i*512 + tid;
                        float* d = sCh + (buf^1)*4224 + (e4 >> 4)*66 + ((e4 & 15) << 2);
                        *(float2*)d = make_float2(bufB[i].x, bufB[i].y);
                        *(float2*)(d+2) = make_float2(bufB[i].z, bufB[i].w);
                    }
                    __syncthreads();
                    buf ^= 1;
                }
            }
            __syncthreads();
            #pragma unroll
            for (int q = 0; q < 12; ++q)
                sCh[((ch*12 + q)*64 + rr1)*4 + ksl] = acc[q];
            __syncthreads();
            for (int u = tid; u < 1536; u += 512){
                int cl = u >> 6, r = u & 63;
                const float* qd = sCh + (cl*64 + r)*4;
                float v = qd[0] + qd[1] + qd[2] + qd[3];
                int col = jbase + cl;
                if (col < 2560){
                    sG[cl*64 + r] = v;
                } else {
                    int cj = col - 2560;
                    float jv = tanhf(v + aload_f(&encPT[(size_t)cj*128 + R0 + r]) + bj[cj]);
                    astore_f(&jointT[(size_t)cj*128 + R0 + r], jv);
                }
            }
        }
        gsync();   // B1

        // ================= P2: 16 cols x 32 rows, jointT chunk-staged, Wout cached =================
        {
            float acc[4] = {0,0,0,0};
            f32x4 jb4[4];
            // chunk 0 stage
            #pragma unroll
            for (int i = 0; i < 4; ++i){
                int e4 = i*512 + tid;
                GLD4(jb4[i], jointT + (size_t)(e4 >> 3)*128 + RQ + ((e4 & 7) << 2));
            }
            WAIT0;
            #pragma unroll
            for (int i = 0; i < 4; ++i){
                int e4 = i*512 + tid;
                float* d = sCh + (e4 >> 3)*34 + ((e4 & 7) << 2);
                *(float2*)d = make_float2(jb4[i].x, jb4[i].y);
                *(float2*)(d+2) = make_float2(jb4[i].z, jb4[i].w);
            }
            __syncthreads();
            int col0 = lcg*16 + cq2*4;
            for (int cc = 0; cc < 2; ++cc){
                if (cc == 0){   // prefetch chunk 1 into regs
                    #pragma unroll
                    for (int i = 0; i < 4; ++i){
                        int e4 = i*512 + tid;
                        GLD4(jb4[i], jointT + (size_t)(256 + (e4 >> 3))*128 + RQ + ((e4 & 7) << 2));
                    }
                }
                #pragma unroll 8
                for (int kk = 0; kk < 64; ++kk){
                    int kl = ks2*64 + kk;
                    float jv = sCh[kl*34 + rr2];
                    float4 w4 = *(const float4*)(Wout + (size_t)(cc*256 + kl)*1024 + col0);
                    acc[0] += jv*w4.x; acc[1] += jv*w4.y; acc[2] += jv*w4.z; acc[3] += jv*w4.w;
                }
                if (cc == 0){
                    WAIT0;
                    __syncthreads();
                    #pragma unroll
                    for (int i = 0; i < 4; ++i){
                        int e4 = i*512 + tid;
                        float* d = sCh + (e4 >> 3)*34 + ((e4 & 7) << 2);
                        *(float2*)d = make_float2(jb4[i].x, jb4[i].y);
                        *(float2*)(d+2) = make_float2(jb4[i].z, jb4[i].w);
                    }
                    __syncthreads();
                }
            }
            #pragma unroll
            for (int q = 0; q < 4; ++q)
                sP2[((cq2*4 + q)*32 + rr2)*4 + ks2] = acc[q];
            __syncthreads();
            {
                int c = tid >> 5, r = tid & 31;
                const float* qd = sP2 + (c*32 + r)*4;
                float lg = qd[0] + qd[1] + qd[2] + qd[3];
                float ex = expf(lg);
                int col = lcg*16 + c;
                bool force = sNEm[RQ + r] >= 2;
                int idx; float va;
                if (col == 0){ idx = 1024; va = lg; }
                else { idx = col; va = force ? LOWV : lg; }
                sKX[c*32 + r] = ((u64)fkey(va) << 32) | (unsigned)(2047 - idx);
                sEX[c*32 + r] = ex;
            }
            __syncthreads();
            if (tid < 32){
                u64 m = sKX[tid]; float es = sEX[tid];
                #pragma unroll
                for (int q = 1; q < 16; ++q){
                    u64 o = sKX[q*32 + tid]; if (o > m) m = o;
                    es += sEX[q*32 + tid];
                }
                atomicMax(&packedP[((size_t)s*128 + RQ + tid)*8], m);
                atomicAdd(&sumexpP[((size_t)s*128 + RQ + tid)*16], es);
            }
        }
        gsync();   // B2

        // ================= P3: replica update | LSTM | enc-proj | scorer =================
        if (tid < 128){
            int r = tid;
            u64 pk = aload_u64(&packedP[((size_t)s*128 + r)*8]);
            int tok = 2047 - (int)(unsigned)(pk & 0xffffffffu);
            int act = sAct[r];
            int isb = (tok == 1024);
            sTok[r] = tok < 1023 ? tok : 1023;
            sUpd[r] = act && !isb;
            int et = sEncT[r], ne = sNEm[r], act_n = act, adv = -1;
            if (act){
                et += isb;
                ne = isb ? 0 : ne + 1;
                act_n = (et < sLen[r]) ? 1 : 0;
                if (isb && act_n) adv = et;
            }
            sAdv[r] = adv;
            sAct[r] = act_n; sEncT[r] = et; sNEm[r] = ne;
            if (cg == 127 && (r >> 6) == rg){
                int tok_out = 1024;
                if (act){
                    float val = funkey((unsigned)(pk >> 32));
                    float se = aload_f(&sumexpP[((size_t)s*128 + r)*16]);
                    scReg += val - logf(se);
                    tok_out = (act_n || isb) ? tok : 1024;
                }
                out[(size_t)r*48 + s] = (float)tok_out;
                if (s == 47) out[6144 + r] = scReg;
            }
        }
        __syncthreads();
        if (nj > 0 && tid < nj*64){
            int jj = tid >> 6, r = tid & 63, R = R0 + r;
            float h2;
            if (sUpd[R]){
                float4 ew = EWi4[(size_t)sTok[R]*640 + j0 + jj];
                float gi = sG[(jj*4+0)*64 + r] + ew.x;
                float gf = sG[(jj*4+1)*64 + r] + ew.y;
                float gv = sG[(jj*4+2)*64 + r] + ew.z;
                float go = sG[(jj*4+3)*64 + r] + ew.w;
                float cold = sC[jj*64 + r];
                float cn = sigf(gf)*cold + sigf(gi)*tanhf(gv);
                h2 = tanhf(cn)*sigf(go);
                sC[jj*64 + r] = cn;
            } else {
                h2 = aload_f(&hp[(size_t)(j0+jj)*128 + R]);
            }
            astore_f(&hT[(size_t)w*81920 + (size_t)(j0+jj)*128 + R], h2);
        }
        {   // lazy enc-proj: 2 cols x 128 rows per block (blank rows only)
            int ec0 = bid*2;
            for (int r = wv; r < 128; r += 8){
                int t = sAdv[r];
                if (t < 0) continue;
                const float* er = enc + ((size_t)r*160 + t)*1024;
                const float* w0p = WencT + (size_t)ec0*1024;
                const float* w1p = w0p + 1024;
                float a0 = 0.f, a1 = 0.f;
                int k4 = lane*4;
                #pragma unroll
                for (int i = 0; i < 4; ++i){
                    int k = i*256 + k4;
                    float4 ev = *(const float4*)(er + k);
                    float4 wa = *(const float4*)(w0p + k);
                    float4 wb = *(const float4*)(w1p + k);
                    a0 += ev.x*wa.x + ev.y*wa.y + ev.z*wa.z + ev.w*wa.w;
                    a1 += ev.x*wb.x + ev.y*wb.y + ev.z*wb.z + ev.w*wb.w;
                }
                #pragma unroll
                for (int off = 32; off; off >>= 1){ a0 += __shfl_xor(a0, off, 64); a1 += __shfl_xor(a1, off, 64); }
                if (lane == 0){
                    astore_f(&encPT[(size_t)ec0*128 + r], a0);
                    astore_f(&encPT[(size_t)(ec0+1)*128 + r], a1);
                }
            }
        }
        gsync();   // B3
    }
}

extern "C" void kernel_launch(void* const* d_in, const int* in_sizes, int n_in,
                              void* d_out, int out_size, void* d_ws, size_t ws_size,
                              hipStream_t stream) {
    const float* enc   = (const float*)d_in[0];
    const int*   lens  = (const int*)  d_in[1];
    const float* E     = (const float*)d_in[3];
    const float* Wi    = (const float*)d_in[4];
    const float* Wh    = (const float*)d_in[5];
    const float* bi    = (const float*)d_in[6];
    const float* bh    = (const float*)d_in[7];
    const float* Wenc  = (const float*)d_in[8];
    const float* Wpred = (const float*)d_in[9];
    const float* bj    = (const float*)d_in[10];
    const float* Wout  = (const float*)d_in[11];
    float* out = (float*)d_out;

    char* base = (char*)d_ws;
    size_t off = 0;
    auto carve = [&](size_t bytes) -> void* {
        void* pp = base + off;
        off += (bytes + 255) & ~(size_t)255;
        return pp;
    };
    float*  WT24  = (float*)carve((size_t)128*640*24*4);   // 7.9 MB
    float*  WencT = (float*)carve((size_t)512*1024*4);
    float4* EWi4  = (float4*)carve((size_t)1024*640*16);   // 10.5 MB
    float*  hT    = (float*)carve((size_t)2*640*128*4);
    float*  encPT = (float*)carve((size_t)512*128*4);
    float*  jointT= (float*)carve((size_t)512*128*4);
    u64*    packedP = (u64*)carve((size_t)48*128*8*8);     // 64B/row
    float*  sumexpP = (float*)carve((size_t)48*128*16*4);  // 64B/row
    int*    cntZ  = (int*)carve(544*4);
    (void)ws_size; (void)in_sizes; (void)n_in; (void)out_size;

    k_rm <<<7680, 256, 0, stream>>>(Wh, Wpred, WT24, cntZ);
    k_trE<<<128,  256, 0, stream>>>(Wenc, WencT);
    k_ewi<<<1280, 256, 0, stream>>>(E, Wi, bi, bh, EWi4);
    k_is <<<86,   512, 0, stream>>>(enc, WencT, encPT);
    mega <<<NBLK, 512, 0, stream>>>(enc, lens, bj, WT24, Wout, WencT, EWi4,
                                    hT, encPT, jointT, packedP, sumexpP, cntZ, out);
}